// Round 1
// baseline (38.655 us; speedup 1.0000x reference)
//
#include <hip/hip_runtime.h>
#include <math.h>

// Problem constants (fixed by setup_inputs): B=1024, S=4096, C=5
#define PB 1024
#define PS 4096
#define PC 5
#define PAIRS_PER_BLOCK 255            // block covers 256 timesteps -> 255 pairs
#define BPR ((PS - 1 + PAIRS_PER_BLOCK - 1) / PAIRS_PER_BLOCK)   // 17 blocks per row
#define NBLOCKS (PB * BPR)             // 17408
#define LAMBDA 0.3f

__global__ __launch_bounds__(256) void tc_pair_kernel(
    const float* __restrict__ logits,
    const float* __restrict__ trans,
    float* __restrict__ partials)
{
    __shared__ float sh[256][13];   // [tid][0..4]=probs, [5..9]=logp ; stride 13 -> 2-way banks (free)
    __shared__ float sT[25];
    __shared__ float red[4];

    const int tid = threadIdx.x;
    const int b   = blockIdx.x / BPR;
    const int j   = blockIdx.x - b * BPR;
    const int t0  = j * PAIRS_PER_BLOCK;
    const int t   = t0 + tid;

    if (tid < 25) sT[tid] = trans[tid];

    float p0=0,p1=0,p2=0,p3=0,p4=0;
    float q0=0,q1=0,q2=0,q3=0,q4=0;   // logp

    if (t < PS) {
        const float* ptr = logits + ((size_t)b * PS + (size_t)t) * PC;
        const float l0 = ptr[0], l1 = ptr[1], l2 = ptr[2], l3 = ptr[3], l4 = ptr[4];
        const float m  = fmaxf(fmaxf(fmaxf(l0, l1), fmaxf(l2, l3)), l4);
        const float e0 = __expf(l0 - m), e1 = __expf(l1 - m), e2 = __expf(l2 - m),
                    e3 = __expf(l3 - m), e4 = __expf(l4 - m);
        const float s   = e0 + e1 + e2 + e3 + e4;
        const float inv = __frcp_rn(s);
        const float ls  = __logf(s);
        p0 = e0 * inv; p1 = e1 * inv; p2 = e2 * inv; p3 = e3 * inv; p4 = e4 * inv;
        q0 = (l0 - m) - ls; q1 = (l1 - m) - ls; q2 = (l2 - m) - ls;
        q3 = (l3 - m) - ls; q4 = (l4 - m) - ls;
        sh[tid][0] = p0; sh[tid][1] = p1; sh[tid][2] = p2; sh[tid][3] = p3; sh[tid][4] = p4;
        sh[tid][5] = q0; sh[tid][6] = q1; sh[tid][7] = q2; sh[tid][8] = q3; sh[tid][9] = q4;
    }
    __syncthreads();

    float local = 0.0f;
    if (tid < PAIRS_PER_BLOCK && (t0 + tid) < PS - 1) {
        // curr = neighbor's softmax
        const float c0 = sh[tid+1][0], c1 = sh[tid+1][1], c2 = sh[tid+1][2],
                    c3 = sh[tid+1][3], c4 = sh[tid+1][4];
        const float d0 = sh[tid+1][5], d1 = sh[tid+1][6], d2 = sh[tid+1][7],
                    d3 = sh[tid+1][8], d4 = sh[tid+1][9];

        // smooth: sum_c |prev - curr|
        float smooth = fabsf(p0 - c0) + fabsf(p1 - c1) + fabsf(p2 - c2)
                     + fabsf(p3 - c3) + fabsf(p4 - c4);

        // expected[d] = sum_c prev[c] * T[c][d]
        float kl = 0.0f;
        #pragma unroll
        for (int d = 0; d < PC; ++d) {
            const float e = p0 * sT[0*PC + d] + p1 * sT[1*PC + d] + p2 * sT[2*PC + d]
                          + p3 * sT[3*PC + d] + p4 * sT[4*PC + d];
            const float lpc = (d == 0) ? d0 : (d == 1) ? d1 : (d == 2) ? d2 : (d == 3) ? d3 : d4;
            if (e > 0.0f) kl += e * (__logf(e) - lpc);
        }
        local = smooth + kl;
    }

    // wave reduce (wave64)
    #pragma unroll
    for (int off = 32; off > 0; off >>= 1)
        local += __shfl_down(local, off, 64);
    if ((tid & 63) == 0) red[tid >> 6] = local;
    __syncthreads();
    if (tid == 0)
        partials[blockIdx.x] = red[0] + red[1] + red[2] + red[3];
}

__global__ __launch_bounds__(1024) void tc_reduce_kernel(
    const float* __restrict__ partials, float* __restrict__ out)
{
    __shared__ double sred[1024];
    double acc = 0.0;
    for (int i = threadIdx.x; i < NBLOCKS; i += 1024)
        acc += (double)partials[i];
    sred[threadIdx.x] = acc;
    __syncthreads();
    for (int s = 512; s > 0; s >>= 1) {
        if (threadIdx.x < s) sred[threadIdx.x] += sred[threadIdx.x + s];
        __syncthreads();
    }
    if (threadIdx.x == 0) {
        const double N = (double)PB * (double)(PS - 1);
        out[0] = (float)((double)LAMBDA * sred[0] / N);
    }
}

extern "C" void kernel_launch(void* const* d_in, const int* in_sizes, int n_in,
                              void* d_out, int out_size, void* d_ws, size_t ws_size,
                              hipStream_t stream) {
    const float* logits = (const float*)d_in[0];
    const float* trans  = (const float*)d_in[1];
    float* out = (float*)d_out;
    float* partials = (float*)d_ws;   // NBLOCKS floats = 69,632 B

    tc_pair_kernel<<<NBLOCKS, 256, 0, stream>>>(logits, trans, partials);
    tc_reduce_kernel<<<1, 1024, 0, stream>>>(partials, out);
}